// Round 13
// baseline (339.366 us; speedup 1.0000x reference)
//
#include <hip/hip_runtime.h>
#include <math.h>

// TripletLoss N=8192, D=128, labels in [0,512). Round 16: VALU tree + fuse.
//   r15 resolved the plateau: occupancy (8 blocks/CU via 17.4KB LDS +
//   natural 64-VGPR codegen) -> 89.9us best. Now VALU-issue is the floor
//   (~40 cyc epilogue vs 20 cyc MFMA per tile). This round:
//   1) epilogue tree: masked values + balanced fmin/fmax tree (clang fuses
//      v_min3/v_max3, T17); dep chain 4->2.
//   2) reduce folded into pair (done-ticket): last block finalizes all
//      8192 rows reading extremes via PURE-RMW atomic reads
//      (atomicMin(p,UINT_MAX)/atomicMax(p,0)) — the XCD-coherence-safe way
//      to read other blocks' atomic results within one kernel.
//   2 graph nodes: prep, pair.
// Self-pair never wins hp (u_self=+0.5*sq_i is max-u; hp takes min-u);
// validity hpE!=PINF && hnE!=NINF == reference any(pos)&&any(neg).
// Note: harness poisons the 256MB workspace (~42us fillBuffer) inside the
// timed window every iteration — a floor we don't control.

#define NROWS 8192
#define DIM   128
#define JSPLIT 64
#define JCHUNK (NROWS / JSPLIT)   // 128 j per y-block
#define NSUB   4                  // 32-row subtiles per j-chunk
#define SUBROWS 32
#define NBLK   (32 * JSPLIT)      // 2048 pair blocks

typedef short bf16x8 __attribute__((ext_vector_type(8)));
typedef float f32x4  __attribute__((ext_vector_type(4)));

static __device__ __forceinline__ unsigned short f2bf(float f) {
    unsigned u = __float_as_uint(f);
    unsigned r = (u + 0x7FFFu + ((u >> 16) & 1u)) >> 16;   // RNE
    return (unsigned short)r;
}

// order-preserving float<->uint encoding: unsigned compare == float compare
static __device__ __forceinline__ unsigned encf(float f) {
    unsigned u = __float_as_uint(f);
    return (u & 0x80000000u) ? ~u : (u | 0x80000000u);
}
static __device__ __forceinline__ float decf(unsigned e) {
    unsigned u = (e & 0x80000000u) ? (e & 0x7FFFFFFFu) : ~e;
    return __uint_as_float(u);
}
#define ENC_PINF 0xFF800000u   // encf(+INF) — init for min
#define ENC_NINF 0x007FFFFFu   // encf(-INF) — init for max

static __device__ __forceinline__ void gload_lds16(const void* g, void* l) {
    __builtin_amdgcn_global_load_lds(
        (const __attribute__((address_space(1))) unsigned int*)g,
        (__attribute__((address_space(3))) unsigned int*)l, 16, 0, 0);
}

// ---------------- K1: prep — sq, bf16, minmax init -----------------------
__global__ __launch_bounds__(256) void prep_kernel(
    const float* __restrict__ x, float* __restrict__ sqp,
    float* __restrict__ sqh, unsigned* __restrict__ hpE,
    unsigned* __restrict__ hnE, unsigned short* __restrict__ xb,
    unsigned* __restrict__ done) {
    int t = blockIdx.x * 256 + threadIdx.x;
    int row = t >> 5;
    int c = t & 31;
    float4 v = ((const float4*)x)[t];
    float ps = v.x * v.x + v.y * v.y + v.z * v.z + v.w * v.w;
#pragma unroll
    for (int s = 1; s < 32; s <<= 1) ps += __shfl_xor(ps, s, 64);
    if (c == 0) {
        sqp[row] = ps;
        sqh[row] = -0.5f * ps;
    } else if (c == 1) {
        hpE[row] = ENC_PINF;
    } else if (c == 2) {
        hnE[row] = ENC_NINF;
    } else if (t == 3) {
        *done = 0u;
    }
    ushort4 ob;
    ob.x = f2bf(v.x); ob.y = f2bf(v.y); ob.z = f2bf(v.z); ob.w = f2bf(v.w);
    ((ushort4*)xb)[t] = ob;
}

// ---------------- K2: pair kernel + fused final reduce -------------------
__global__ __launch_bounds__(256, 4) void pair_kernel(
    const unsigned short* __restrict__ xb, const float* __restrict__ sqh,
    const float* __restrict__ sqp, const int* __restrict__ labels,
    unsigned* __restrict__ hpE, unsigned* __restrict__ hnE,
    unsigned* __restrict__ done, float* __restrict__ out) {
    __shared__ __attribute__((aligned(16))) unsigned char abuf[2][SUBROWS * 256];
    __shared__ __attribute__((aligned(16))) float sqs[JCHUNK];
    __shared__ __attribute__((aligned(16))) int labs[JCHUNK];
    __shared__ int isLast;
    __shared__ float ss[4], sc[4];

    const int tid = threadIdx.x;
    const int lane = tid & 63;
    const int wid = tid >> 6;        // 0..3
    const int q = lane >> 4;         // 0..3
    const int r = lane & 15;
    const int ibase = blockIdx.x * 256 + wid * 64;
    const int jbase = blockIdx.y * JCHUNK;

    if (tid < JCHUNK) {
        sqs[tid] = sqh[jbase + tid];     // -0.5*sq_j
        labs[tid] = labels[jbase + tid];
    }

    // B-frags (i side).
    bf16x8 bfrag[4][4];
    int labi[4];
#pragma unroll
    for (int sub = 0; sub < 4; ++sub) {
        int irow = ibase + sub * 16 + r;
        labi[sub] = labels[irow];
#pragma unroll
        for (int ks = 0; ks < 4; ++ks)
            bfrag[sub][ks] = *(const bf16x8*)(xb + (size_t)irow * DIM + ks * 32 + q * 8);
    }

    float hp[4] = {INFINITY, INFINITY, INFINITY, INFINITY};     // min u (pos)
    float hn[4] = {-INFINITY, -INFINITY, -INFINITY, -INFINITY}; // max u (neg)

    // Stage subtile s (32 rows x 128 bf16 = 8 KB), swizzled source
    // (rule 21): LDS[row][c] = G[row][c ^ ((row&15)<<4)], linear dest.
    auto stage = [&](int s, int buf) {
        const char* gb = (const char*)xb + (size_t)(jbase + s * SUBROWS) * 256;
        unsigned char* lb = &abuf[buf][0];
#pragma unroll
        for (int p = 0; p < 2; ++p) {
            int row = wid * 8 + p * 4 + (lane >> 4);
            int colb = (lane & 15) * 16;
            const void* g = gb + row * 256 + (colb ^ ((row & 15) << 4));
            void* l = lb + wid * 2048 + p * 1024;   // wave-uniform base
            gload_lds16(g, l);
        }
    };

    auto compute_tile = [&](int s, int buf, int t) {
        const unsigned char* lb = &abuf[buf][0];
        const int tt = s * 2 + t;    // 16-row tile index within chunk, 0..7
        bf16x8 af[4];
        const int rowb = (t * 16 + r) * 256;
        const int sw = r << 4;       // (row&15)<<4, row = t*16+r
#pragma unroll
        for (int ks = 0; ks < 4; ++ks)
            af[ks] = *(const bf16x8*)(lb + rowb + ((ks * 64 + q * 16) ^ sw));
        f32x4 ci = *(const f32x4*)(&sqs[tt * 16 + q * 4]);
        int4 labj = *(const int4*)(labs + tt * 16 + q * 4);
#pragma unroll
        for (int sub = 0; sub < 4; ++sub) {
            f32x4 acc = ci;
            acc = __builtin_amdgcn_mfma_f32_16x16x32_bf16(af[0], bfrag[sub][0], acc, 0, 0, 0);
            acc = __builtin_amdgcn_mfma_f32_16x16x32_bf16(af[1], bfrag[sub][1], acc, 0, 0, 0);
            acc = __builtin_amdgcn_mfma_f32_16x16x32_bf16(af[2], bfrag[sub][2], acc, 0, 0, 0);
            acc = __builtin_amdgcn_mfma_f32_16x16x32_bf16(af[3], bfrag[sub][3], acc, 0, 0, 0);
            const int li = labi[sub];
            // masked values + balanced tree (min3/max3-friendly, dep 2)
            float m0 = (labj.x == li) ? acc[0] : INFINITY;
            float m1 = (labj.y == li) ? acc[1] : INFINITY;
            float m2 = (labj.z == li) ? acc[2] : INFINITY;
            float m3 = (labj.w == li) ? acc[3] : INFINITY;
            hp[sub] = fminf(hp[sub], fminf(fminf(m0, m1), fminf(m2, m3)));
            float n0 = (labj.x == li) ? -INFINITY : acc[0];
            float n1 = (labj.y == li) ? -INFINITY : acc[1];
            float n2 = (labj.z == li) ? -INFINITY : acc[2];
            float n3 = (labj.w == li) ? -INFINITY : acc[3];
            hn[sub] = fmaxf(hn[sub], fmaxf(fmaxf(n0, n1), fmaxf(n2, n3)));
        }
    };

    // two-barrier pipeline: stage(s+1) in flight while computing s;
    // first barrier also publishes sqs/labs.
    stage(0, 0);
    __syncthreads();
#pragma unroll
    for (int s = 0; s < NSUB; ++s) {
        if (s + 1 < NSUB) stage(s + 1, (s + 1) & 1);
#pragma unroll
        for (int t = 0; t < 2; ++t) compute_tile(s, s & 1, t);
        __syncthreads();
    }

    // reduce across the 4 q-groups (lanes r, r+16, r+32, r+48)
#pragma unroll
    for (int sub = 0; sub < 4; ++sub) {
        hp[sub] = fminf(hp[sub], __shfl_xor(hp[sub], 16, 64));
        hp[sub] = fminf(hp[sub], __shfl_xor(hp[sub], 32, 64));
        hn[sub] = fmaxf(hn[sub], __shfl_xor(hn[sub], 16, 64));
        hn[sub] = fmaxf(hn[sub], __shfl_xor(hn[sub], 32, 64));
    }
    if (lane < 16) {
#pragma unroll
        for (int sub = 0; sub < 4; ++sub) {
            int irow = ibase + sub * 16 + lane;
            unsigned ep = encf(hp[sub]);
            if (ep != ENC_PINF) atomicMin(&hpE[irow], ep);
            unsigned en = encf(hn[sub]);
            if (en != ENC_NINF) atomicMax(&hnE[irow], en);
        }
    }

    // -------- fused final reduce: last block finalizes all rows ----------
    __threadfence();
    if (tid == 0) {
        unsigned t = atomicAdd(done, 1u);
        isLast = (t == NBLK - 1);
    }
    __syncthreads();
    if (!isLast) return;

    float sum = 0.f, cnt = 0.f;
    for (int row = tid; row < NROWS; row += 256) {
        // pure-RMW atomic reads: coherent view of other blocks' atomics
        unsigned hpv = atomicMin(&hpE[row], 0xFFFFFFFFu);
        unsigned hnv = atomicMax(&hnE[row], 0u);
        float s = sqp[row];
        if (hpv != ENC_PINF && hnv != ENC_NINF) {   // any(pos) && any(neg)
            float dp = sqrtf(fmaxf(s - 2.f * decf(hpv), 1e-12f));
            float dn = sqrtf(fmaxf(s - 2.f * decf(hnv), 1e-12f));
            sum += fmaxf(dp - dn + 0.3f, 1e-6f);
            cnt += 1.f;
        }
    }
#pragma unroll
    for (int sh = 1; sh < 64; sh <<= 1) {
        sum += __shfl_xor(sum, sh, 64);
        cnt += __shfl_xor(cnt, sh, 64);
    }
    if ((tid & 63) == 0) { ss[tid >> 6] = sum; sc[tid >> 6] = cnt; }
    __syncthreads();
    if (tid == 0) {
        float S = ss[0] + ss[1] + ss[2] + ss[3];
        float C = sc[0] + sc[1] + sc[2] + sc[3];
        out[0] = (C > 0.f) ? S / C : 0.f;
    }
}

extern "C" void kernel_launch(void* const* d_in, const int* in_sizes, int n_in,
                              void* d_out, int out_size, void* d_ws, size_t ws_size,
                              hipStream_t stream) {
    const float* x = (const float*)d_in[0];
    const int* labels = (const int*)d_in[1];
    float* out = (float*)d_out;

    // ws layout (no memset node — prep rewrites all state every iteration):
    //   done @ 0
    //   sqp  @ 4096   (32 KB)
    //   sqh  @ 36864  (32 KB)   -0.5*sq
    //   hpE  @ 69632  (32 KB)   encoded min-u (positives)
    //   hnE  @ 102400 (32 KB)   encoded max-u (negatives)
    //   xb   @ 135168 (2 MB bf16)      total ~2.2 MB
    char* ws = (char*)d_ws;
    unsigned* done = (unsigned*)ws;
    float* sqp = (float*)(ws + 4096);
    float* sqh = (float*)(ws + 36864);
    unsigned* hpE = (unsigned*)(ws + 69632);
    unsigned* hnE = (unsigned*)(ws + 102400);
    unsigned short* xb = (unsigned short*)(ws + 135168);

    prep_kernel<<<(NROWS * 32) / 256, 256, 0, stream>>>(
        x, sqp, sqh, hpE, hnE, xb, done);
    pair_kernel<<<dim3(NROWS / 256, JSPLIT), 256, 0, stream>>>(
        xb, sqh, sqp, labels, hpE, hnE, done, out);
}

// Round 14
// 98.122 us; speedup vs baseline: 3.4586x; 3.4586x over previous
//
#include <hip/hip_runtime.h>
#include <math.h>

// TripletLoss N=8192, D=128, labels in [0,512). Round 17: revert r16's
// fused reduce (its per-block __threadfence = L2 writeback x2048 blocks ->
// WRITE_SIZE 100MB, pair 290us). Structure = r15 (89.9us best): 3 nodes,
// kernel-boundary handoff. Kept from r16: balanced min/max tree epilogue
// (VALU-local, min3/max3-friendly, dep chain 4->2).
//   prep:  sq, -0.5sq, bf16 cast, sentinel init, zero gsum/gcnt/done.
//   pair:  17.4KB LDS dbuf (SUBROWS=32), natural 64-VGPR codegen ->
//          8 blocks/CU = 32 waves (r15's occupancy win), swizzle both
//          sides, global atomicMin/Max merge on encoded floats.
//   reduce: decode + validity + sqrt/margin + block sums -> atomics,
//          done-ticket final -> out.
// Self-pair never wins hp (u_self=+0.5*sq_i is max-u; hp takes min-u);
// validity hpE!=PINF && hnE!=NINF == reference any(pos)&&any(neg).
// Note: harness poisons the 256MB workspace (~42us fillBuffer) inside the
// timed window every iteration — a floor we don't control.

#define NROWS 8192
#define DIM   128
#define JSPLIT 64
#define JCHUNK (NROWS / JSPLIT)   // 128 j per y-block
#define NSUB   4                  // 32-row subtiles per j-chunk
#define SUBROWS 32

typedef short bf16x8 __attribute__((ext_vector_type(8)));
typedef float f32x4  __attribute__((ext_vector_type(4)));

static __device__ __forceinline__ unsigned short f2bf(float f) {
    unsigned u = __float_as_uint(f);
    unsigned r = (u + 0x7FFFu + ((u >> 16) & 1u)) >> 16;   // RNE
    return (unsigned short)r;
}

// order-preserving float<->uint encoding: unsigned compare == float compare
static __device__ __forceinline__ unsigned encf(float f) {
    unsigned u = __float_as_uint(f);
    return (u & 0x80000000u) ? ~u : (u | 0x80000000u);
}
static __device__ __forceinline__ float decf(unsigned e) {
    unsigned u = (e & 0x80000000u) ? (e & 0x7FFFFFFFu) : ~e;
    return __uint_as_float(u);
}
#define ENC_PINF 0xFF800000u   // encf(+INF) — init for min
#define ENC_NINF 0x007FFFFFu   // encf(-INF) — init for max

static __device__ __forceinline__ void gload_lds16(const void* g, void* l) {
    __builtin_amdgcn_global_load_lds(
        (const __attribute__((address_space(1))) unsigned int*)g,
        (__attribute__((address_space(3))) unsigned int*)l, 16, 0, 0);
}

// ---------------- K1: prep — sq, bf16, minmax init, acc zero -------------
__global__ __launch_bounds__(256) void prep_kernel(
    const float* __restrict__ x, float* __restrict__ sqp,
    float* __restrict__ sqh, unsigned* __restrict__ hpE,
    unsigned* __restrict__ hnE, unsigned short* __restrict__ xb,
    float* __restrict__ gsum, float* __restrict__ gcnt,
    unsigned* __restrict__ done) {
    int t = blockIdx.x * 256 + threadIdx.x;
    int row = t >> 5;
    int c = t & 31;
    float4 v = ((const float4*)x)[t];
    float ps = v.x * v.x + v.y * v.y + v.z * v.z + v.w * v.w;
#pragma unroll
    for (int s = 1; s < 32; s <<= 1) ps += __shfl_xor(ps, s, 64);
    if (c == 0) {
        sqp[row] = ps;
        sqh[row] = -0.5f * ps;
    } else if (c == 1) {
        hpE[row] = ENC_PINF;
    } else if (c == 2) {
        hnE[row] = ENC_NINF;
    } else if (t == 3) {
        *gsum = 0.f; *gcnt = 0.f; *done = 0u;
    }
    ushort4 ob;
    ob.x = f2bf(v.x); ob.y = f2bf(v.y); ob.z = f2bf(v.z); ob.w = f2bf(v.w);
    ((ushort4*)xb)[t] = ob;
}

// ---------------- K2: pair kernel (17.4KB LDS, natural 8 blocks/CU) ------
__global__ __launch_bounds__(256, 4) void pair_kernel(
    const unsigned short* __restrict__ xb, const float* __restrict__ sqh,
    const int* __restrict__ labels,
    unsigned* __restrict__ hpE, unsigned* __restrict__ hnE) {
    __shared__ __attribute__((aligned(16))) unsigned char abuf[2][SUBROWS * 256];
    __shared__ __attribute__((aligned(16))) float sqs[JCHUNK];
    __shared__ __attribute__((aligned(16))) int labs[JCHUNK];

    const int tid = threadIdx.x;
    const int lane = tid & 63;
    const int wid = tid >> 6;        // 0..3
    const int q = lane >> 4;         // 0..3
    const int r = lane & 15;
    const int ibase = blockIdx.x * 256 + wid * 64;
    const int jbase = blockIdx.y * JCHUNK;

    if (tid < JCHUNK) {
        sqs[tid] = sqh[jbase + tid];     // -0.5*sq_j
        labs[tid] = labels[jbase + tid];
    }

    // B-frags (i side).
    bf16x8 bfrag[4][4];
    int labi[4];
#pragma unroll
    for (int sub = 0; sub < 4; ++sub) {
        int irow = ibase + sub * 16 + r;
        labi[sub] = labels[irow];
#pragma unroll
        for (int ks = 0; ks < 4; ++ks)
            bfrag[sub][ks] = *(const bf16x8*)(xb + (size_t)irow * DIM + ks * 32 + q * 8);
    }

    float hp[4] = {INFINITY, INFINITY, INFINITY, INFINITY};     // min u (pos)
    float hn[4] = {-INFINITY, -INFINITY, -INFINITY, -INFINITY}; // max u (neg)

    // Stage subtile s (32 rows x 128 bf16 = 8 KB), swizzled source
    // (rule 21): LDS[row][c] = G[row][c ^ ((row&15)<<4)], linear dest.
    auto stage = [&](int s, int buf) {
        const char* gb = (const char*)xb + (size_t)(jbase + s * SUBROWS) * 256;
        unsigned char* lb = &abuf[buf][0];
#pragma unroll
        for (int p = 0; p < 2; ++p) {
            int row = wid * 8 + p * 4 + (lane >> 4);
            int colb = (lane & 15) * 16;
            const void* g = gb + row * 256 + (colb ^ ((row & 15) << 4));
            void* l = lb + wid * 2048 + p * 1024;   // wave-uniform base
            gload_lds16(g, l);
        }
    };

    auto compute_tile = [&](int s, int buf, int t) {
        const unsigned char* lb = &abuf[buf][0];
        const int tt = s * 2 + t;    // 16-row tile index within chunk, 0..7
        bf16x8 af[4];
        const int rowb = (t * 16 + r) * 256;
        const int sw = r << 4;       // (row&15)<<4, row = t*16+r
#pragma unroll
        for (int ks = 0; ks < 4; ++ks)
            af[ks] = *(const bf16x8*)(lb + rowb + ((ks * 64 + q * 16) ^ sw));
        f32x4 ci = *(const f32x4*)(&sqs[tt * 16 + q * 4]);
        int4 labj = *(const int4*)(labs + tt * 16 + q * 4);
#pragma unroll
        for (int sub = 0; sub < 4; ++sub) {
            f32x4 acc = ci;
            acc = __builtin_amdgcn_mfma_f32_16x16x32_bf16(af[0], bfrag[sub][0], acc, 0, 0, 0);
            acc = __builtin_amdgcn_mfma_f32_16x16x32_bf16(af[1], bfrag[sub][1], acc, 0, 0, 0);
            acc = __builtin_amdgcn_mfma_f32_16x16x32_bf16(af[2], bfrag[sub][2], acc, 0, 0, 0);
            acc = __builtin_amdgcn_mfma_f32_16x16x32_bf16(af[3], bfrag[sub][3], acc, 0, 0, 0);
            const int li = labi[sub];
            // masked values + balanced tree (min3/max3-friendly, dep 2)
            float m0 = (labj.x == li) ? acc[0] : INFINITY;
            float m1 = (labj.y == li) ? acc[1] : INFINITY;
            float m2 = (labj.z == li) ? acc[2] : INFINITY;
            float m3 = (labj.w == li) ? acc[3] : INFINITY;
            hp[sub] = fminf(hp[sub], fminf(fminf(m0, m1), fminf(m2, m3)));
            float n0 = (labj.x == li) ? -INFINITY : acc[0];
            float n1 = (labj.y == li) ? -INFINITY : acc[1];
            float n2 = (labj.z == li) ? -INFINITY : acc[2];
            float n3 = (labj.w == li) ? -INFINITY : acc[3];
            hn[sub] = fmaxf(hn[sub], fmaxf(fmaxf(n0, n1), fmaxf(n2, n3)));
        }
    };

    // two-barrier pipeline: stage(s+1) in flight while computing s;
    // first barrier also publishes sqs/labs.
    stage(0, 0);
    __syncthreads();
#pragma unroll
    for (int s = 0; s < NSUB; ++s) {
        if (s + 1 < NSUB) stage(s + 1, (s + 1) & 1);
#pragma unroll
        for (int t = 0; t < 2; ++t) compute_tile(s, s & 1, t);
        __syncthreads();
    }

    // reduce across the 4 q-groups (lanes r, r+16, r+32, r+48)
#pragma unroll
    for (int sub = 0; sub < 4; ++sub) {
        hp[sub] = fminf(hp[sub], __shfl_xor(hp[sub], 16, 64));
        hp[sub] = fminf(hp[sub], __shfl_xor(hp[sub], 32, 64));
        hn[sub] = fmaxf(hn[sub], __shfl_xor(hn[sub], 16, 64));
        hn[sub] = fmaxf(hn[sub], __shfl_xor(hn[sub], 32, 64));
    }
    if (lane < 16) {
#pragma unroll
        for (int sub = 0; sub < 4; ++sub) {
            int irow = ibase + sub * 16 + lane;
            unsigned ep = encf(hp[sub]);
            if (ep != ENC_PINF) atomicMin(&hpE[irow], ep);
            unsigned en = encf(hn[sub]);
            if (en != ENC_NINF) atomicMax(&hnE[irow], en);
        }
    }
}

// ---------------- K3: reduce + fused final ------------------------------
__global__ __launch_bounds__(256) void reduce_kernel(
    const unsigned* __restrict__ hpE, const unsigned* __restrict__ hnE,
    const float* __restrict__ sqp, float* __restrict__ gsum,
    float* __restrict__ gcnt, unsigned* __restrict__ done,
    float* __restrict__ out) {
    int row = blockIdx.x * 256 + threadIdx.x;
    unsigned hpv = hpE[row];
    unsigned hnv = hnE[row];
    float s = sqp[row];
    float sum = 0.f, cnt = 0.f;
    if (hpv != ENC_PINF && hnv != ENC_NINF) {   // == any(pos) && any(neg)
        float dp = sqrtf(fmaxf(s - 2.f * decf(hpv), 1e-12f));
        float dn = sqrtf(fmaxf(s - 2.f * decf(hnv), 1e-12f));
        sum = fmaxf(dp - dn + 0.3f, 1e-6f);
        cnt = 1.f;
    }
#pragma unroll
    for (int sh = 1; sh < 64; sh <<= 1) {
        sum += __shfl_xor(sum, sh, 64);
        cnt += __shfl_xor(cnt, sh, 64);
    }
    __shared__ float ss[4], sc[4];
    int w = threadIdx.x >> 6;
    if ((threadIdx.x & 63) == 0) { ss[w] = sum; sc[w] = cnt; }
    __syncthreads();
    if (threadIdx.x == 0) {
        atomicAdd(gsum, ss[0] + ss[1] + ss[2] + ss[3]);
        atomicAdd(gcnt, sc[0] + sc[1] + sc[2] + sc[3]);
        __threadfence();
        unsigned t = atomicAdd(done, 1u);
        if (t == gridDim.x - 1) {
            float S = atomicAdd(gsum, 0.f);   // coherent read via RMW
            float C = atomicAdd(gcnt, 0.f);
            out[0] = (C > 0.f) ? S / C : 0.f;
        }
    }
}

extern "C" void kernel_launch(void* const* d_in, const int* in_sizes, int n_in,
                              void* d_out, int out_size, void* d_ws, size_t ws_size,
                              hipStream_t stream) {
    const float* x = (const float*)d_in[0];
    const int* labels = (const int*)d_in[1];
    float* out = (float*)d_out;

    // ws layout (no memset node — prep rewrites all state every iteration):
    //   gsum @ 0, gcnt @ 4, done @ 8
    //   sqp  @ 4096   (32 KB)
    //   sqh  @ 36864  (32 KB)   -0.5*sq
    //   hpE  @ 69632  (32 KB)   encoded min-u (positives)
    //   hnE  @ 102400 (32 KB)   encoded max-u (negatives)
    //   xb   @ 135168 (2 MB bf16)      total ~2.2 MB
    char* ws = (char*)d_ws;
    float* gsum = (float*)ws;
    float* gcnt = (float*)(ws + 4);
    unsigned* done = (unsigned*)(ws + 8);
    float* sqp = (float*)(ws + 4096);
    float* sqh = (float*)(ws + 36864);
    unsigned* hpE = (unsigned*)(ws + 69632);
    unsigned* hnE = (unsigned*)(ws + 102400);
    unsigned short* xb = (unsigned short*)(ws + 135168);

    prep_kernel<<<(NROWS * 32) / 256, 256, 0, stream>>>(
        x, sqp, sqh, hpE, hnE, xb, gsum, gcnt, done);
    pair_kernel<<<dim3(NROWS / 256, JSPLIT), 256, 0, stream>>>(
        xb, sqh, labels, hpE, hnE);
    reduce_kernel<<<NROWS / 256, 256, 0, stream>>>(
        hpE, hnE, sqp, gsum, gcnt, done, out);
}

// Round 15
// 92.521 us; speedup vs baseline: 3.6680x; 1.0605x over previous
//
#include <hip/hip_runtime.h>
#include <math.h>

// TripletLoss N=8192, D=128, labels in [0,512). Round 18: store commit.
//   r17 exposed pair at 45us with WRITE_SIZE=51MB: device-scope
//   atomicMin/Max write through toward memory-side for XCD coherence
//   (~64B per atomic x 524K commits). Fix: revert to r0's plain-store
//   partial commit — hpp/hnp[JSPLIT][NROWS] f32, coalesced, 4MB total,
//   zero atomics in pair; reduce scans the 64 partials per row (L2/L3
//   resident). Also reverted r17's epilogue tree (+8us vs r15's chain).
//   Core = r15 (best 89.9): 17.4KB LDS dbuf, SUBROWS=32, JSPLIT=64,
//   2048 blocks -> 8 blocks/CU, natural 64-VGPR codegen, swizzle both
//   sides, two-barrier pipeline.
// Validity: row valid iff min-partial != +INF && max-partial != -INF
// (== reference any(pos)&&any(neg)); hist stays deleted. Self-pair never
// wins hp (u_self=+0.5*sq_i is max-u; hp takes min-u).
// Note: harness poisons the 256MB workspace (~42us fillBuffer) inside the
// timed window every iteration — a floor we don't control.

#define NROWS 8192
#define DIM   128
#define JSPLIT 64
#define JCHUNK (NROWS / JSPLIT)   // 128 j per y-block
#define NSUB   4                  // 32-row subtiles per j-chunk
#define SUBROWS 32

typedef short bf16x8 __attribute__((ext_vector_type(8)));
typedef float f32x4  __attribute__((ext_vector_type(4)));

static __device__ __forceinline__ unsigned short f2bf(float f) {
    unsigned u = __float_as_uint(f);
    unsigned r = (u + 0x7FFFu + ((u >> 16) & 1u)) >> 16;   // RNE
    return (unsigned short)r;
}

static __device__ __forceinline__ void gload_lds16(const void* g, void* l) {
    __builtin_amdgcn_global_load_lds(
        (const __attribute__((address_space(1))) unsigned int*)g,
        (__attribute__((address_space(3))) unsigned int*)l, 16, 0, 0);
}

// ---------------- K1: prep — sq, bf16, zero accumulators -----------------
__global__ __launch_bounds__(256) void prep_kernel(
    const float* __restrict__ x, float* __restrict__ sqp,
    float* __restrict__ sqh, unsigned short* __restrict__ xb,
    float* __restrict__ gsum, float* __restrict__ gcnt,
    unsigned* __restrict__ done) {
    int t = blockIdx.x * 256 + threadIdx.x;
    int row = t >> 5;
    int c = t & 31;
    float4 v = ((const float4*)x)[t];
    float ps = v.x * v.x + v.y * v.y + v.z * v.z + v.w * v.w;
#pragma unroll
    for (int s = 1; s < 32; s <<= 1) ps += __shfl_xor(ps, s, 64);
    if (c == 0) {
        sqp[row] = ps;
        sqh[row] = -0.5f * ps;
    } else if (t == 1) {
        *gsum = 0.f; *gcnt = 0.f; *done = 0u;
    }
    ushort4 ob;
    ob.x = f2bf(v.x); ob.y = f2bf(v.y); ob.z = f2bf(v.z); ob.w = f2bf(v.w);
    ((ushort4*)xb)[t] = ob;
}

// ---------------- K2: pair kernel (17.4KB LDS, 8 blocks/CU, stores) ------
__global__ __launch_bounds__(256, 4) void pair_kernel(
    const unsigned short* __restrict__ xb, const float* __restrict__ sqh,
    const int* __restrict__ labels,
    float* __restrict__ hpp, float* __restrict__ hnp) {
    __shared__ __attribute__((aligned(16))) unsigned char abuf[2][SUBROWS * 256];
    __shared__ __attribute__((aligned(16))) float sqs[JCHUNK];
    __shared__ __attribute__((aligned(16))) int labs[JCHUNK];

    const int tid = threadIdx.x;
    const int lane = tid & 63;
    const int wid = tid >> 6;        // 0..3
    const int q = lane >> 4;         // 0..3
    const int r = lane & 15;
    const int ibase = blockIdx.x * 256 + wid * 64;
    const int jbase = blockIdx.y * JCHUNK;

    if (tid < JCHUNK) {
        sqs[tid] = sqh[jbase + tid];     // -0.5*sq_j
        labs[tid] = labels[jbase + tid];
    }

    // B-frags (i side).
    bf16x8 bfrag[4][4];
    int labi[4];
#pragma unroll
    for (int sub = 0; sub < 4; ++sub) {
        int irow = ibase + sub * 16 + r;
        labi[sub] = labels[irow];
#pragma unroll
        for (int ks = 0; ks < 4; ++ks)
            bfrag[sub][ks] = *(const bf16x8*)(xb + (size_t)irow * DIM + ks * 32 + q * 8);
    }

    float hp[4] = {INFINITY, INFINITY, INFINITY, INFINITY};     // min u (pos)
    float hn[4] = {-INFINITY, -INFINITY, -INFINITY, -INFINITY}; // max u (neg)

    // Stage subtile s (32 rows x 128 bf16 = 8 KB), swizzled source
    // (rule 21): LDS[row][c] = G[row][c ^ ((row&15)<<4)], linear dest.
    auto stage = [&](int s, int buf) {
        const char* gb = (const char*)xb + (size_t)(jbase + s * SUBROWS) * 256;
        unsigned char* lb = &abuf[buf][0];
#pragma unroll
        for (int p = 0; p < 2; ++p) {
            int row = wid * 8 + p * 4 + (lane >> 4);
            int colb = (lane & 15) * 16;
            const void* g = gb + row * 256 + (colb ^ ((row & 15) << 4));
            void* l = lb + wid * 2048 + p * 1024;   // wave-uniform base
            gload_lds16(g, l);
        }
    };

    auto compute_tile = [&](int s, int buf, int t) {
        const unsigned char* lb = &abuf[buf][0];
        const int tt = s * 2 + t;    // 16-row tile index within chunk, 0..7
        bf16x8 af[4];
        const int rowb = (t * 16 + r) * 256;
        const int sw = r << 4;       // (row&15)<<4, row = t*16+r
#pragma unroll
        for (int ks = 0; ks < 4; ++ks)
            af[ks] = *(const bf16x8*)(lb + rowb + ((ks * 64 + q * 16) ^ sw));
        f32x4 ci = *(const f32x4*)(&sqs[tt * 16 + q * 4]);
        int4 labj = *(const int4*)(labs + tt * 16 + q * 4);
#pragma unroll
        for (int sub = 0; sub < 4; ++sub) {
            f32x4 acc = ci;
            acc = __builtin_amdgcn_mfma_f32_16x16x32_bf16(af[0], bfrag[sub][0], acc, 0, 0, 0);
            acc = __builtin_amdgcn_mfma_f32_16x16x32_bf16(af[1], bfrag[sub][1], acc, 0, 0, 0);
            acc = __builtin_amdgcn_mfma_f32_16x16x32_bf16(af[2], bfrag[sub][2], acc, 0, 0, 0);
            acc = __builtin_amdgcn_mfma_f32_16x16x32_bf16(af[3], bfrag[sub][3], acc, 0, 0, 0);
            const int li = labi[sub];
            float u0 = acc[0], u1 = acc[1], u2 = acc[2], u3 = acc[3];
            hp[sub] = fminf(hp[sub], (labj.x == li) ? u0 : INFINITY);
            hn[sub] = fmaxf(hn[sub], (labj.x == li) ? -INFINITY : u0);
            hp[sub] = fminf(hp[sub], (labj.y == li) ? u1 : INFINITY);
            hn[sub] = fmaxf(hn[sub], (labj.y == li) ? -INFINITY : u1);
            hp[sub] = fminf(hp[sub], (labj.z == li) ? u2 : INFINITY);
            hn[sub] = fmaxf(hn[sub], (labj.z == li) ? -INFINITY : u2);
            hp[sub] = fminf(hp[sub], (labj.w == li) ? u3 : INFINITY);
            hn[sub] = fmaxf(hn[sub], (labj.w == li) ? -INFINITY : u3);
        }
    };

    // two-barrier pipeline: stage(s+1) in flight while computing s;
    // first barrier also publishes sqs/labs.
    stage(0, 0);
    __syncthreads();
#pragma unroll
    for (int s = 0; s < NSUB; ++s) {
        if (s + 1 < NSUB) stage(s + 1, (s + 1) & 1);
#pragma unroll
        for (int t = 0; t < 2; ++t) compute_tile(s, s & 1, t);
        __syncthreads();
    }

    // reduce across the 4 q-groups (lanes r, r+16, r+32, r+48)
#pragma unroll
    for (int sub = 0; sub < 4; ++sub) {
        hp[sub] = fminf(hp[sub], __shfl_xor(hp[sub], 16, 64));
        hp[sub] = fminf(hp[sub], __shfl_xor(hp[sub], 32, 64));
        hn[sub] = fmaxf(hn[sub], __shfl_xor(hn[sub], 16, 64));
        hn[sub] = fmaxf(hn[sub], __shfl_xor(hn[sub], 32, 64));
    }
    if (lane < 16) {
        const int pbase = blockIdx.y * NROWS;
#pragma unroll
        for (int sub = 0; sub < 4; ++sub) {
            int irow = ibase + sub * 16 + lane;
            hpp[pbase + irow] = hp[sub];    // plain coalesced stores,
            hnp[pbase + irow] = hn[sub];    // zero atomics in pair
        }
    }
}

// ---------------- K3: reduce + fused final ------------------------------
__global__ __launch_bounds__(256) void reduce_kernel(
    const float* __restrict__ hpp, const float* __restrict__ hnp,
    const float* __restrict__ sqp, float* __restrict__ gsum,
    float* __restrict__ gcnt, unsigned* __restrict__ done,
    float* __restrict__ out) {
    int row = blockIdx.x * 256 + threadIdx.x;
    float mnp = INFINITY, mxn = -INFINITY;
#pragma unroll 8
    for (int p = 0; p < JSPLIT; ++p) {
        mnp = fminf(mnp, hpp[p * NROWS + row]);
        mxn = fmaxf(mxn, hnp[p * NROWS + row]);
    }
    float s = sqp[row];
    float sum = 0.f, cnt = 0.f;
    if (mnp != INFINITY && mxn != -INFINITY) {   // any(pos) && any(neg)
        float dp = sqrtf(fmaxf(s - 2.f * mnp, 1e-12f));
        float dn = sqrtf(fmaxf(s - 2.f * mxn, 1e-12f));
        sum = fmaxf(dp - dn + 0.3f, 1e-6f);
        cnt = 1.f;
    }
#pragma unroll
    for (int sh = 1; sh < 64; sh <<= 1) {
        sum += __shfl_xor(sum, sh, 64);
        cnt += __shfl_xor(cnt, sh, 64);
    }
    __shared__ float ss[4], sc[4];
    int w = threadIdx.x >> 6;
    if ((threadIdx.x & 63) == 0) { ss[w] = sum; sc[w] = cnt; }
    __syncthreads();
    if (threadIdx.x == 0) {
        atomicAdd(gsum, ss[0] + ss[1] + ss[2] + ss[3]);
        atomicAdd(gcnt, sc[0] + sc[1] + sc[2] + sc[3]);
        __threadfence();
        unsigned t = atomicAdd(done, 1u);
        if (t == gridDim.x - 1) {
            float S = atomicAdd(gsum, 0.f);   // coherent read via RMW
            float C = atomicAdd(gcnt, 0.f);
            out[0] = (C > 0.f) ? S / C : 0.f;
        }
    }
}

extern "C" void kernel_launch(void* const* d_in, const int* in_sizes, int n_in,
                              void* d_out, int out_size, void* d_ws, size_t ws_size,
                              hipStream_t stream) {
    const float* x = (const float*)d_in[0];
    const int* labels = (const int*)d_in[1];
    float* out = (float*)d_out;

    // ws layout (no memset node; every hpp/hnp slot written by pair):
    //   gsum @ 0, gcnt @ 4, done @ 8
    //   sqp  @ 4096     (32 KB)
    //   sqh  @ 36864    (32 KB)   -0.5*sq
    //   hpp  @ 69632    (2 MB)    [JSPLIT x NROWS] f32 partial min-u
    //   hnp  @ 2166784  (2 MB)    [JSPLIT x NROWS] f32 partial max-u
    //   xb   @ 4263936  (2 MB bf16)      total ~6.3 MB
    char* ws = (char*)d_ws;
    float* gsum = (float*)ws;
    float* gcnt = (float*)(ws + 4);
    unsigned* done = (unsigned*)(ws + 8);
    float* sqp = (float*)(ws + 4096);
    float* sqh = (float*)(ws + 36864);
    float* hpp = (float*)(ws + 69632);
    float* hnp = (float*)(ws + 2166784);
    unsigned short* xb = (unsigned short*)(ws + 4263936);

    prep_kernel<<<(NROWS * 32) / 256, 256, 0, stream>>>(
        x, sqp, sqh, xb, gsum, gcnt, done);
    pair_kernel<<<dim3(NROWS / 256, JSPLIT), 256, 0, stream>>>(
        xb, sqh, labels, hpp, hnp);
    reduce_kernel<<<NROWS / 256, 256, 0, stream>>>(
        hpp, hnp, sqp, gsum, gcnt, done, out);
}

// Round 16
// 89.552 us; speedup vs baseline: 3.7896x; 1.0332x over previous
//
#include <hip/hip_runtime.h>
#include <math.h>

// TripletLoss N=8192, D=128, labels in [0,512). Round 19: consolidation —
// restore round-15 verbatim (session best, 89.9us), after the r17/r18 A/B
// showed both the epilogue tree (+8) and the store-commit+scan (+2.6)
// regress vs this configuration.
//   prep:  sq, -0.5sq, bf16 cast, sentinel init, zero gsum/gcnt/done.
//   pair:  17.4KB LDS dbuf (SUBROWS=32, JSPLIT=64, 2048 blocks), natural
//          64-VGPR codegen -> 8 blocks/CU = 32 waves/CU (the occupancy
//          win that produced 89.9), XOR swizzle both sides (rule 21),
//          two-barrier pipeline, global atomicMin/Max merge on encoded
//          floats (write-through cost hidden under latency slack — r18
//          A/B confirmed it beats plain-store+scan).
//   reduce: decode + validity + sqrt/margin + done-ticket final.
// Self-pair never wins hp (u_self=+0.5*sq_i is max-u; hp takes min-u);
// validity hpE!=PINF && hnE!=NINF == reference any(pos)&&any(neg).
// Session ledger on pair: occupancy fix +8us (real); epilogue thinning,
// residency 3->4, 16-slot swizzle, counted vmcnt, bfrag pin, XCD swizzle
// all neutral; triangle, fence-fused reduce, tree, store-commit negative.
// Note: harness poisons the 256MB workspace (~42us fillBuffer) inside the
// timed window every iteration — a floor we don't control.

#define NROWS 8192
#define DIM   128
#define JSPLIT 64
#define JCHUNK (NROWS / JSPLIT)   // 128 j per y-block
#define NSUB   4                  // 32-row subtiles per j-chunk
#define SUBROWS 32

typedef short bf16x8 __attribute__((ext_vector_type(8)));
typedef float f32x4  __attribute__((ext_vector_type(4)));

static __device__ __forceinline__ unsigned short f2bf(float f) {
    unsigned u = __float_as_uint(f);
    unsigned r = (u + 0x7FFFu + ((u >> 16) & 1u)) >> 16;   // RNE
    return (unsigned short)r;
}

// order-preserving float<->uint encoding: unsigned compare == float compare
static __device__ __forceinline__ unsigned encf(float f) {
    unsigned u = __float_as_uint(f);
    return (u & 0x80000000u) ? ~u : (u | 0x80000000u);
}
static __device__ __forceinline__ float decf(unsigned e) {
    unsigned u = (e & 0x80000000u) ? (e & 0x7FFFFFFFu) : ~e;
    return __uint_as_float(u);
}
#define ENC_PINF 0xFF800000u   // encf(+INF) — init for min
#define ENC_NINF 0x007FFFFFu   // encf(-INF) — init for max

static __device__ __forceinline__ void gload_lds16(const void* g, void* l) {
    __builtin_amdgcn_global_load_lds(
        (const __attribute__((address_space(1))) unsigned int*)g,
        (__attribute__((address_space(3))) unsigned int*)l, 16, 0, 0);
}

// ---------------- K1: prep — sq, bf16, minmax init, acc zero -------------
__global__ __launch_bounds__(256) void prep_kernel(
    const float* __restrict__ x, float* __restrict__ sqp,
    float* __restrict__ sqh, unsigned* __restrict__ hpE,
    unsigned* __restrict__ hnE, unsigned short* __restrict__ xb,
    float* __restrict__ gsum, float* __restrict__ gcnt,
    unsigned* __restrict__ done) {
    int t = blockIdx.x * 256 + threadIdx.x;
    int row = t >> 5;
    int c = t & 31;
    float4 v = ((const float4*)x)[t];
    float ps = v.x * v.x + v.y * v.y + v.z * v.z + v.w * v.w;
#pragma unroll
    for (int s = 1; s < 32; s <<= 1) ps += __shfl_xor(ps, s, 64);
    if (c == 0) {
        sqp[row] = ps;
        sqh[row] = -0.5f * ps;
    } else if (c == 1) {
        hpE[row] = ENC_PINF;
    } else if (c == 2) {
        hnE[row] = ENC_NINF;
    } else if (t == 3) {
        *gsum = 0.f; *gcnt = 0.f; *done = 0u;
    }
    ushort4 ob;
    ob.x = f2bf(v.x); ob.y = f2bf(v.y); ob.z = f2bf(v.z); ob.w = f2bf(v.w);
    ((ushort4*)xb)[t] = ob;
}

// ---------------- K2: pair kernel (17.4KB LDS, natural 8 blocks/CU) ------
__global__ __launch_bounds__(256, 4) void pair_kernel(
    const unsigned short* __restrict__ xb, const float* __restrict__ sqh,
    const int* __restrict__ labels,
    unsigned* __restrict__ hpE, unsigned* __restrict__ hnE) {
    __shared__ __attribute__((aligned(16))) unsigned char abuf[2][SUBROWS * 256];
    __shared__ __attribute__((aligned(16))) float sqs[JCHUNK];
    __shared__ __attribute__((aligned(16))) int labs[JCHUNK];

    const int tid = threadIdx.x;
    const int lane = tid & 63;
    const int wid = tid >> 6;        // 0..3
    const int q = lane >> 4;         // 0..3
    const int r = lane & 15;
    const int ibase = blockIdx.x * 256 + wid * 64;
    const int jbase = blockIdx.y * JCHUNK;

    if (tid < JCHUNK) {
        sqs[tid] = sqh[jbase + tid];     // -0.5*sq_j
        labs[tid] = labels[jbase + tid];
    }

    // B-frags (i side).
    bf16x8 bfrag[4][4];
    int labi[4];
#pragma unroll
    for (int sub = 0; sub < 4; ++sub) {
        int irow = ibase + sub * 16 + r;
        labi[sub] = labels[irow];
#pragma unroll
        for (int ks = 0; ks < 4; ++ks)
            bfrag[sub][ks] = *(const bf16x8*)(xb + (size_t)irow * DIM + ks * 32 + q * 8);
    }

    float hp[4] = {INFINITY, INFINITY, INFINITY, INFINITY};     // min u (pos)
    float hn[4] = {-INFINITY, -INFINITY, -INFINITY, -INFINITY}; // max u (neg)

    // Stage subtile s (32 rows x 128 bf16 = 8 KB), swizzled source
    // (rule 21): LDS[row][c] = G[row][c ^ ((row&15)<<4)], linear dest.
    auto stage = [&](int s, int buf) {
        const char* gb = (const char*)xb + (size_t)(jbase + s * SUBROWS) * 256;
        unsigned char* lb = &abuf[buf][0];
#pragma unroll
        for (int p = 0; p < 2; ++p) {
            int row = wid * 8 + p * 4 + (lane >> 4);
            int colb = (lane & 15) * 16;
            const void* g = gb + row * 256 + (colb ^ ((row & 15) << 4));
            void* l = lb + wid * 2048 + p * 1024;   // wave-uniform base
            gload_lds16(g, l);
        }
    };

    auto compute_tile = [&](int s, int buf, int t) {
        const unsigned char* lb = &abuf[buf][0];
        const int tt = s * 2 + t;    // 16-row tile index within chunk, 0..7
        bf16x8 af[4];
        const int rowb = (t * 16 + r) * 256;
        const int sw = r << 4;       // (row&15)<<4, row = t*16+r
#pragma unroll
        for (int ks = 0; ks < 4; ++ks)
            af[ks] = *(const bf16x8*)(lb + rowb + ((ks * 64 + q * 16) ^ sw));
        f32x4 ci = *(const f32x4*)(&sqs[tt * 16 + q * 4]);
        int4 labj = *(const int4*)(labs + tt * 16 + q * 4);
#pragma unroll
        for (int sub = 0; sub < 4; ++sub) {
            f32x4 acc = ci;
            acc = __builtin_amdgcn_mfma_f32_16x16x32_bf16(af[0], bfrag[sub][0], acc, 0, 0, 0);
            acc = __builtin_amdgcn_mfma_f32_16x16x32_bf16(af[1], bfrag[sub][1], acc, 0, 0, 0);
            acc = __builtin_amdgcn_mfma_f32_16x16x32_bf16(af[2], bfrag[sub][2], acc, 0, 0, 0);
            acc = __builtin_amdgcn_mfma_f32_16x16x32_bf16(af[3], bfrag[sub][3], acc, 0, 0, 0);
            const int li = labi[sub];
            float u0 = acc[0], u1 = acc[1], u2 = acc[2], u3 = acc[3];
            hp[sub] = fminf(hp[sub], (labj.x == li) ? u0 : INFINITY);
            hn[sub] = fmaxf(hn[sub], (labj.x == li) ? -INFINITY : u0);
            hp[sub] = fminf(hp[sub], (labj.y == li) ? u1 : INFINITY);
            hn[sub] = fmaxf(hn[sub], (labj.y == li) ? -INFINITY : u1);
            hp[sub] = fminf(hp[sub], (labj.z == li) ? u2 : INFINITY);
            hn[sub] = fmaxf(hn[sub], (labj.z == li) ? -INFINITY : u2);
            hp[sub] = fminf(hp[sub], (labj.w == li) ? u3 : INFINITY);
            hn[sub] = fmaxf(hn[sub], (labj.w == li) ? -INFINITY : u3);
        }
    };

    // two-barrier pipeline: stage(s+1) in flight while computing s;
    // first barrier also publishes sqs/labs.
    stage(0, 0);
    __syncthreads();
#pragma unroll
    for (int s = 0; s < NSUB; ++s) {
        if (s + 1 < NSUB) stage(s + 1, (s + 1) & 1);
#pragma unroll
        for (int t = 0; t < 2; ++t) compute_tile(s, s & 1, t);
        __syncthreads();
    }

    // reduce across the 4 q-groups (lanes r, r+16, r+32, r+48)
#pragma unroll
    for (int sub = 0; sub < 4; ++sub) {
        hp[sub] = fminf(hp[sub], __shfl_xor(hp[sub], 16, 64));
        hp[sub] = fminf(hp[sub], __shfl_xor(hp[sub], 32, 64));
        hn[sub] = fmaxf(hn[sub], __shfl_xor(hn[sub], 16, 64));
        hn[sub] = fmaxf(hn[sub], __shfl_xor(hn[sub], 32, 64));
    }
    if (lane < 16) {
#pragma unroll
        for (int sub = 0; sub < 4; ++sub) {
            int irow = ibase + sub * 16 + lane;
            unsigned ep = encf(hp[sub]);
            if (ep != ENC_PINF) atomicMin(&hpE[irow], ep);
            unsigned en = encf(hn[sub]);
            if (en != ENC_NINF) atomicMax(&hnE[irow], en);
        }
    }
}

// ---------------- K3: reduce + fused final ------------------------------
__global__ __launch_bounds__(256) void reduce_kernel(
    const unsigned* __restrict__ hpE, const unsigned* __restrict__ hnE,
    const float* __restrict__ sqp, float* __restrict__ gsum,
    float* __restrict__ gcnt, unsigned* __restrict__ done,
    float* __restrict__ out) {
    int row = blockIdx.x * 256 + threadIdx.x;
    unsigned hpv = hpE[row];
    unsigned hnv = hnE[row];
    float s = sqp[row];
    float sum = 0.f, cnt = 0.f;
    if (hpv != ENC_PINF && hnv != ENC_NINF) {   // == any(pos) && any(neg)
        float dp = sqrtf(fmaxf(s - 2.f * decf(hpv), 1e-12f));
        float dn = sqrtf(fmaxf(s - 2.f * decf(hnv), 1e-12f));
        sum = fmaxf(dp - dn + 0.3f, 1e-6f);
        cnt = 1.f;
    }
#pragma unroll
    for (int sh = 1; sh < 64; sh <<= 1) {
        sum += __shfl_xor(sum, sh, 64);
        cnt += __shfl_xor(cnt, sh, 64);
    }
    __shared__ float ss[4], sc[4];
    int w = threadIdx.x >> 6;
    if ((threadIdx.x & 63) == 0) { ss[w] = sum; sc[w] = cnt; }
    __syncthreads();
    if (threadIdx.x == 0) {
        atomicAdd(gsum, ss[0] + ss[1] + ss[2] + ss[3]);
        atomicAdd(gcnt, sc[0] + sc[1] + sc[2] + sc[3]);
        __threadfence();
        unsigned t = atomicAdd(done, 1u);
        if (t == gridDim.x - 1) {
            float S = atomicAdd(gsum, 0.f);   // coherent read via RMW
            float C = atomicAdd(gcnt, 0.f);
            out[0] = (C > 0.f) ? S / C : 0.f;
        }
    }
}

extern "C" void kernel_launch(void* const* d_in, const int* in_sizes, int n_in,
                              void* d_out, int out_size, void* d_ws, size_t ws_size,
                              hipStream_t stream) {
    const float* x = (const float*)d_in[0];
    const int* labels = (const int*)d_in[1];
    float* out = (float*)d_out;

    // ws layout (no memset node — prep rewrites all state every iteration):
    //   gsum @ 0, gcnt @ 4, done @ 8
    //   sqp  @ 4096   (32 KB)
    //   sqh  @ 36864  (32 KB)   -0.5*sq
    //   hpE  @ 69632  (32 KB)   encoded min-u (positives)
    //   hnE  @ 102400 (32 KB)   encoded max-u (negatives)
    //   xb   @ 135168 (2 MB bf16)      total ~2.2 MB
    char* ws = (char*)d_ws;
    float* gsum = (float*)ws;
    float* gcnt = (float*)(ws + 4);
    unsigned* done = (unsigned*)(ws + 8);
    float* sqp = (float*)(ws + 4096);
    float* sqh = (float*)(ws + 36864);
    unsigned* hpE = (unsigned*)(ws + 69632);
    unsigned* hnE = (unsigned*)(ws + 102400);
    unsigned short* xb = (unsigned short*)(ws + 135168);

    prep_kernel<<<(NROWS * 32) / 256, 256, 0, stream>>>(
        x, sqp, sqh, hpE, hnE, xb, gsum, gcnt, done);
    pair_kernel<<<dim3(NROWS / 256, JSPLIT), 256, 0, stream>>>(
        xb, sqh, labels, hpE, hnE);
    reduce_kernel<<<NROWS / 256, 256, 0, stream>>>(
        hpE, hnE, sqp, gsum, gcnt, done, out);
}